// Round 1
// baseline (376.748 us; speedup 1.0000x reference)
//
#include <hip/hip_runtime.h>
#include <hip/hip_bf16.h>

#define L_SZ 1024
#define P_SZ 2048
#define HID 256
#define NH 8
#define HD 32
#define NRBF 50

typedef unsigned int uint32;

__constant__ float kINV_SCALE = 0.17677669529663687f; // 1/sqrt(32)

static __device__ __forceinline__ float u2f(uint32 u) { return __uint_as_float(u); }
static __device__ __forceinline__ unsigned short f2bf(float f) {
    uint32 x = __float_as_uint(f);
    x += 0x7fffu + ((x >> 16) & 1u);   // round-to-nearest-even
    return (unsigned short)(x >> 16);
}
static __device__ __forceinline__ float bf2f(unsigned short u) {
    return __uint_as_float(((uint32)u) << 16);
}

// ---------------------------------------------------------------------------
// Kernel 1: Q = lig@Wq+bq (f32), K = prot@Wk+bk (bf16), V = prot@Wv+bv (bf16)
// 64 threads/block, 8 rows/block, 4 cols/thread.
// ---------------------------------------------------------------------------
__global__ __launch_bounds__(64) void k_proj(
    const float* __restrict__ lig, const float* __restrict__ prot,
    const float* __restrict__ Wq, const float* __restrict__ bq,
    const float* __restrict__ Wk, const float* __restrict__ bk,
    const float* __restrict__ Wv, const float* __restrict__ bv,
    float* __restrict__ Qf, unsigned short* __restrict__ Kb,
    unsigned short* __restrict__ Vb)
{
    __shared__ float As[8 * HID];
    const int t = threadIdx.x;
    const int r0 = blockIdx.x * 8;

    const float* src; const float* W; const float* bias; int mode; int row0;
    if (r0 < L_SZ)            { src = lig  + (size_t)r0 * HID;               W = Wq; bias = bq; mode = 0; row0 = r0; }
    else if (r0 < L_SZ + P_SZ){ src = prot + (size_t)(r0 - L_SZ) * HID;      W = Wk; bias = bk; mode = 1; row0 = r0 - L_SZ; }
    else                      { src = prot + (size_t)(r0 - L_SZ - P_SZ)*HID; W = Wv; bias = bv; mode = 2; row0 = r0 - L_SZ - P_SZ; }

    float4* A4 = (float4*)As;
    const float4* S4 = (const float4*)src;
    #pragma unroll
    for (int j = 0; j < 8; ++j) A4[t + j * 64] = S4[t + j * 64];
    __syncthreads();

    float acc[8][4];
    #pragma unroll
    for (int r = 0; r < 8; ++r)
        #pragma unroll
        for (int c = 0; c < 4; ++c) acc[r][c] = 0.f;

    for (int k4 = 0; k4 < 64; ++k4) {
        float4 av[8];
        #pragma unroll
        for (int r = 0; r < 8; ++r) av[r] = A4[r * 64 + k4];
        #pragma unroll
        for (int kk = 0; kk < 4; ++kk) {
            const float* wr = W + (size_t)(k4 * 4 + kk) * HID + t;
            #pragma unroll
            for (int c = 0; c < 4; ++c) {
                float wv = wr[c * 64];
                #pragma unroll
                for (int r = 0; r < 8; ++r)
                    acc[r][c] += ((const float*)&av[r])[kk] * wv;
            }
        }
    }

    #pragma unroll
    for (int c = 0; c < 4; ++c) {
        const int col = t + c * 64;
        const float bb = bias[col];
        #pragma unroll
        for (int r = 0; r < 8; ++r) {
            float v = acc[r][c] + bb;
            size_t idx = (size_t)(row0 + r) * HID + col;
            if (mode == 0)      Qf[idx] = v;
            else if (mode == 1) Kb[idx] = f2bf(v);
            else                Vb[idx] = f2bf(v);
        }
    }
}

// ---------------------------------------------------------------------------
// Kernel 2: fused bias(rbf@Wrbf) + QK^T + softmax + weights-out + PV
// One block per ligand row l. 256 threads. Logits live in registers.
// ---------------------------------------------------------------------------
__global__ __launch_bounds__(256) void k_attn(
    const float* __restrict__ rbf, const float* __restrict__ Qf,
    const unsigned short* __restrict__ Kb, const unsigned short* __restrict__ Vb,
    const float* __restrict__ Wrbf, const float* __restrict__ brbf,
    float* __restrict__ attn_out, float* __restrict__ att_ws)
{
    __shared__ unsigned short lw[P_SZ * NH];  // 32 KB, weights as bf16
    __shared__ float redA[4][NH];
    __shared__ float redB[4][NH];
    __shared__ float pvs[4][NH][HD];          // 4 KB

    const int l = blockIdx.x;
    const int t = threadIdx.x;
    const int lane = t & 63;
    const int wv = t >> 6;

    float lg[8][NH];
    #pragma unroll
    for (int h = 0; h < NH; ++h) {
        const float bb = brbf[h];
        #pragma unroll
        for (int i = 0; i < 8; ++i) lg[i][h] = bb;
    }

    // ---- dist_bias = rbf @ Wrbf (rbf direct from global; Wrbf via s_loads) ----
    #pragma unroll
    for (int i = 0; i < 8; ++i) {
        const int p = i * 256 + t;
        const float2* rp = (const float2*)(rbf + ((size_t)l * P_SZ + p) * NRBF);
        for (int j = 0; j < 25; ++j) {
            float2 v = rp[j];
            const float* wr = Wrbf + (2 * j) * NH;
            #pragma unroll
            for (int h = 0; h < NH; ++h)
                lg[i][h] += v.x * wr[h] + v.y * wr[NH + h];
        }
    }

    // ---- QK^T / scale (q row via uniform s_loads, K bf16 from L2) ----
    const float* qrow = Qf + (size_t)l * HID;
    #pragma unroll
    for (int h = 0; h < NH; ++h) {
        #pragma unroll
        for (int i = 0; i < 8; ++i) {
            const int p = i * 256 + t;
            const uint4* kp = (const uint4*)(Kb + (size_t)p * HID + h * HD);
            float qk = 0.f;
            #pragma unroll
            for (int jw = 0; jw < 4; ++jw) {
                uint4 kv = kp[jw];
                const float* qq = qrow + h * HD + jw * 8;
                qk += u2f(kv.x << 16)          * qq[0];
                qk += u2f(kv.x & 0xffff0000u)  * qq[1];
                qk += u2f(kv.y << 16)          * qq[2];
                qk += u2f(kv.y & 0xffff0000u)  * qq[3];
                qk += u2f(kv.z << 16)          * qq[4];
                qk += u2f(kv.z & 0xffff0000u)  * qq[5];
                qk += u2f(kv.w << 16)          * qq[6];
                qk += u2f(kv.w & 0xffff0000u)  * qq[7];
            }
            lg[i][h] += qk * kINV_SCALE;
        }
    }

    // ---- softmax max (wave butterfly + cross-wave LDS) ----
    float m[NH];
    #pragma unroll
    for (int h = 0; h < NH; ++h) {
        float mm = lg[0][h];
        #pragma unroll
        for (int i = 1; i < 8; ++i) mm = fmaxf(mm, lg[i][h]);
        #pragma unroll
        for (int msk = 1; msk < 64; msk <<= 1) mm = fmaxf(mm, __shfl_xor(mm, msk));
        m[h] = mm;
    }
    if (lane == 0) {
        #pragma unroll
        for (int h = 0; h < NH; ++h) redA[wv][h] = m[h];
    }
    __syncthreads();
    #pragma unroll
    for (int h = 0; h < NH; ++h)
        m[h] = fmaxf(fmaxf(redA[0][h], redA[1][h]), fmaxf(redA[2][h], redA[3][h]));

    // ---- exp + sum ----
    float sinv[NH];
    #pragma unroll
    for (int h = 0; h < NH; ++h) {
        float ss = 0.f;
        #pragma unroll
        for (int i = 0; i < 8; ++i) { lg[i][h] = __expf(lg[i][h] - m[h]); ss += lg[i][h]; }
        #pragma unroll
        for (int msk = 1; msk < 64; msk <<= 1) ss += __shfl_xor(ss, msk);
        sinv[h] = ss;
    }
    if (lane == 0) {
        #pragma unroll
        for (int h = 0; h < NH; ++h) redB[wv][h] = sinv[h];
    }
    __syncthreads();
    #pragma unroll
    for (int h = 0; h < NH; ++h)
        sinv[h] = 1.0f / (redB[0][h] + redB[1][h] + redB[2][h] + redB[3][h]);

    // ---- normalized weights: f32 coalesced global write + bf16 into LDS ----
    #pragma unroll
    for (int i = 0; i < 8; ++i) {
        const int p = i * 256 + t;
        float w[NH];
        #pragma unroll
        for (int h = 0; h < NH; ++h) w[h] = lg[i][h] * sinv[h];
        float4* op = (float4*)(attn_out + ((size_t)l * P_SZ + p) * NH);
        op[0] = make_float4(w[0], w[1], w[2], w[3]);
        op[1] = make_float4(w[4], w[5], w[6], w[7]);
        uint4 pk;
        pk.x = (uint32)f2bf(w[0]) | ((uint32)f2bf(w[1]) << 16);
        pk.y = (uint32)f2bf(w[2]) | ((uint32)f2bf(w[3]) << 16);
        pk.z = (uint32)f2bf(w[4]) | ((uint32)f2bf(w[5]) << 16);
        pk.w = (uint32)f2bf(w[6]) | ((uint32)f2bf(w[7]) << 16);
        ((uint4*)lw)[p] = pk;
    }
    __syncthreads();

    // ---- PV: attended[h][d] = sum_p w[p][h] * V[p][h*32+d] ----
    const int hv = t & 7;
    const int pbase = t >> 3;
    float acc[HD];
    #pragma unroll
    for (int d = 0; d < HD; ++d) acc[d] = 0.f;
    for (int ii = 0; ii < 64; ++ii) {
        const int p = ii * 32 + pbase;
        const float w = bf2f(lw[p * NH + hv]);
        const uint4* vp = (const uint4*)(Vb + (size_t)p * HID + hv * HD);
        #pragma unroll
        for (int jw = 0; jw < 4; ++jw) {
            uint4 vvv = vp[jw];
            acc[jw * 8 + 0] += w * u2f(vvv.x << 16);
            acc[jw * 8 + 1] += w * u2f(vvv.x & 0xffff0000u);
            acc[jw * 8 + 2] += w * u2f(vvv.y << 16);
            acc[jw * 8 + 3] += w * u2f(vvv.y & 0xffff0000u);
            acc[jw * 8 + 4] += w * u2f(vvv.z << 16);
            acc[jw * 8 + 5] += w * u2f(vvv.z & 0xffff0000u);
            acc[jw * 8 + 6] += w * u2f(vvv.w << 16);
            acc[jw * 8 + 7] += w * u2f(vvv.w & 0xffff0000u);
        }
    }
    #pragma unroll
    for (int d = 0; d < HD; ++d) {
        acc[d] += __shfl_xor(acc[d], 8);
        acc[d] += __shfl_xor(acc[d], 16);
        acc[d] += __shfl_xor(acc[d], 32);
    }
    if (lane < 8) {
        #pragma unroll
        for (int d = 0; d < HD; ++d) pvs[wv][lane][d] = acc[d];
    }
    __syncthreads();
    {
        const int hh = t >> 5, dd = t & 31;
        float a = pvs[0][hh][dd] + pvs[1][hh][dd] + pvs[2][hh][dd] + pvs[3][hh][dd];
        att_ws[(size_t)l * HID + t] = a;
    }
}

// ---------------------------------------------------------------------------
// Kernel 3: y = lig + attended@Wo + bo; LayerNorm(y)*gamma + beta
// ---------------------------------------------------------------------------
__global__ __launch_bounds__(256) void k_out(
    const float* __restrict__ att, const float* __restrict__ lig,
    const float* __restrict__ Wo, const float* __restrict__ bo,
    const float* __restrict__ gamma, const float* __restrict__ beta,
    float* __restrict__ out)
{
    __shared__ float a[HID];
    __shared__ float red[8];
    const int l = blockIdx.x, t = threadIdx.x;
    if (t < 64) ((float4*)a)[t] = ((const float4*)(att + (size_t)l * HID))[t];
    __syncthreads();

    float acc = bo[t];
    for (int k4 = 0; k4 < 64; ++k4) {
        float4 av = ((float4*)a)[k4];
        const float* wr = Wo + (size_t)(k4 * 4) * HID + t;
        acc += av.x * wr[0];
        acc += av.y * wr[HID];
        acc += av.z * wr[2 * HID];
        acc += av.w * wr[3 * HID];
    }
    float y = lig[(size_t)l * HID + t] + acc;

    float s = y, sq = y * y;
    #pragma unroll
    for (int msk = 1; msk < 64; msk <<= 1) {
        s  += __shfl_xor(s, msk);
        sq += __shfl_xor(sq, msk);
    }
    const int lane = t & 63, wvi = t >> 6;
    if (lane == 0) { red[wvi * 2] = s; red[wvi * 2 + 1] = sq; }
    __syncthreads();
    float ts = red[0] + red[2] + red[4] + red[6];
    float tq = red[1] + red[3] + red[5] + red[7];
    float mu = ts * (1.0f / HID);
    float var = tq * (1.0f / HID) - mu * mu;
    out[(size_t)l * HID + t] = (y - mu) * rsqrtf(var + 1e-5f) * gamma[t] + beta[t];
}

// ---------------------------------------------------------------------------
extern "C" void kernel_launch(void* const* d_in, const int* in_sizes, int n_in,
                              void* d_out, int out_size, void* d_ws, size_t ws_size,
                              hipStream_t stream)
{
    (void)in_sizes; (void)n_in; (void)out_size; (void)ws_size;

    const float* lig   = (const float*)d_in[0];
    const float* prot  = (const float*)d_in[1];
    const float* rbf   = (const float*)d_in[2];
    // d_in[3] = L, d_in[4] = P (compile-time constants here)
    const float* Wq    = (const float*)d_in[5];
    const float* bq    = (const float*)d_in[6];
    const float* Wk    = (const float*)d_in[7];
    const float* bk    = (const float*)d_in[8];
    const float* Wv    = (const float*)d_in[9];
    const float* bv    = (const float*)d_in[10];
    const float* Wrbf  = (const float*)d_in[11];
    const float* brbf  = (const float*)d_in[12];
    const float* Wo    = (const float*)d_in[13];
    const float* bo    = (const float*)d_in[14];
    const float* gamma = (const float*)d_in[15];
    const float* beta  = (const float*)d_in[16];

    float* out0 = (float*)d_out;                          // [1024,256]
    float* attn = (float*)d_out + (size_t)L_SZ * HID;     // [1024,2048,8]

    char* ws = (char*)d_ws;
    float*          Qf     = (float*)ws;                          // 1 MB
    unsigned short* Kb     = (unsigned short*)(ws + (1u << 20));  // 1 MB
    unsigned short* Vb     = (unsigned short*)(ws + (2u << 20));  // 1 MB
    float*          att_ws = (float*)(ws + (3u << 20));           // 1 MB

    hipLaunchKernelGGL(k_proj, dim3((L_SZ + 2 * P_SZ) / 8), dim3(64), 0, stream,
                       lig, prot, Wq, bq, Wk, bk, Wv, bv, Qf, Kb, Vb);
    hipLaunchKernelGGL(k_attn, dim3(L_SZ), dim3(256), 0, stream,
                       rbf, Qf, Kb, Vb, Wrbf, brbf, attn, att_ws);
    hipLaunchKernelGGL(k_out, dim3(L_SZ), dim3(256), 0, stream,
                       att_ws, lig, Wo, bo, gamma, beta, out0);
}